// Round 1
// baseline (2752.233 us; speedup 1.0000x reference)
//
#include <hip/hip_runtime.h>

#define N_NODES_C 40000
#define N_EDGES_C 640000
#define DIM 128
#define NB 50
#define NBP 52        // padded basis (multiple of 4)
#define LDA 132       // padded A-tile leading dim (4*132 % 32 = 16 -> bank-spread)
#define BLK 256
#define TROWS 64
#define LOG2_C 0.6931471805599453f
#define PI_OVER_CUT 0.6283185307179586f  // pi/5

__device__ __forceinline__ float ssp_f(float t) {
    // logaddexp(t,0) - log(2), numerically stable
    return fmaxf(t, 0.0f) + log1pf(expf(-fabsf(t))) - LOG2_C;
}

// Stage a 32-row chunk of B[K][128] (row-major) into LDS; rows >= Kreal zeroed.
__device__ __forceinline__ void stage_chunk(const float* __restrict__ B, int k0, int rows,
                                            int Kreal, float* __restrict__ Bc, int tid) {
    const int n4 = rows * (DIM / 4);
    const float4* Bg = (const float4*)B + (size_t)k0 * (DIM / 4);
    float4* Bc4 = (float4*)Bc;
    for (int i = tid; i < n4; i += BLK) {
        int row = k0 + (i >> 5);
        float4 v;
        if (row < Kreal) v = Bg[i];
        else v = make_float4(0.f, 0.f, 0.f, 0.f);
        Bc4[i] = v;
    }
}

// C[64][128] += A_lds[64][lda] (K cols) @ Bglob[K][128], register tile 4x8 per thread.
template <int KPAD, int KREAL>
__device__ __forceinline__ void gemm_tile(const float* __restrict__ A_lds, int lda,
                                          const float* __restrict__ Bglob,
                                          float* __restrict__ Bc,
                                          float acc[4][8], int rt, int ct, int tid) {
    for (int k0 = 0; k0 < KPAD; k0 += 32) {
        const int rows = (KPAD - k0) < 32 ? (KPAD - k0) : 32;
        __syncthreads();                       // previous chunk reads done
        stage_chunk(Bglob, k0, rows, KREAL, Bc, tid);
        __syncthreads();                       // chunk (and any prior LDS writes) visible
        for (int k4 = 0; k4 < rows / 4; ++k4) {
            float4 av[4];
#pragma unroll
            for (int i = 0; i < 4; ++i)
                av[i] = *(const float4*)&A_lds[(rt * 4 + i) * lda + k0 + k4 * 4];
#pragma unroll
            for (int kk = 0; kk < 4; ++kk) {
                const float* bp = &Bc[(k4 * 4 + kk) * DIM + ct * 8];
                float4 b0 = *(const float4*)bp;
                float4 b1 = *(const float4*)(bp + 4);
#pragma unroll
                for (int i = 0; i < 4; ++i) {
                    float a = ((const float*)&av[i])[kk];
                    acc[i][0] += a * b0.x;
                    acc[i][1] += a * b0.y;
                    acc[i][2] += a * b0.z;
                    acc[i][3] += a * b0.w;
                    acc[i][4] += a * b1.x;
                    acc[i][5] += a * b1.y;
                    acc[i][6] += a * b1.z;
                    acc[i][7] += a * b1.w;
                }
            }
        }
    }
}

__device__ __forceinline__ void init_acc_bias(float acc[4][8], const float* __restrict__ b, int ct) {
    float4 bb0 = *(const float4*)&b[ct * 8];
    float4 bb1 = *(const float4*)&b[ct * 8 + 4];
#pragma unroll
    for (int i = 0; i < 4; ++i) {
        acc[i][0] = bb0.x; acc[i][1] = bb0.y; acc[i][2] = bb0.z; acc[i][3] = bb0.w;
        acc[i][4] = bb1.x; acc[i][5] = bb1.y; acc[i][6] = bb1.z; acc[i][7] = bb1.w;
    }
}

// ---------------- Kernel 1: h = x @ W_in2f ----------------
__global__ __launch_bounds__(BLK) void node_in2f_kernel(const float* __restrict__ x,
                                                        const float* __restrict__ W,
                                                        float* __restrict__ h) {
    __shared__ float At[TROWS * LDA];
    __shared__ float Bc[32 * DIM];
    const int tid = threadIdx.x;
    const int rt = tid >> 4, ct = tid & 15;
    const int n0 = blockIdx.x * TROWS;

    // stage x tile (all tiles full: 40000 % 64 == 0)
    for (int i = tid; i < TROWS * (DIM / 4); i += BLK) {
        int row = i >> 5, c4 = i & 31;
        *(float4*)&At[row * LDA + c4 * 4] = *(const float4*)&x[(size_t)(n0 + row) * DIM + c4 * 4];
    }

    float acc[4][8];
#pragma unroll
    for (int i = 0; i < 4; ++i)
#pragma unroll
        for (int j = 0; j < 8; ++j) acc[i][j] = 0.f;

    gemm_tile<DIM, DIM>(At, LDA, W, Bc, acc, rt, ct, tid);

#pragma unroll
    for (int i = 0; i < 4; ++i) {
        float* hp = &h[(size_t)(n0 + rt * 4 + i) * DIM + ct * 8];
        *(float4*)hp = make_float4(acc[i][0], acc[i][1], acc[i][2], acc[i][3]);
        *(float4*)(hp + 4) = make_float4(acc[i][4], acc[i][5], acc[i][6], acc[i][7]);
    }
}

// ---------------- Kernel 2: edges ----------------
__global__ __launch_bounds__(BLK) void edge_kernel(const float* __restrict__ f_ij,
                                                   const float* __restrict__ r_ij,
                                                   const int* __restrict__ ind_i,
                                                   const int* __restrict__ ind_j,
                                                   const float* __restrict__ W_f1,
                                                   const float* __restrict__ b_f1,
                                                   const float* __restrict__ W_f2,
                                                   const float* __restrict__ b_f2,
                                                   const float* __restrict__ h,
                                                   float* __restrict__ agg) {
    __shared__ float fA[TROWS * NBP];   // 13.3 KB
    __shared__ float t1[TROWS * LDA];   // 33.8 KB
    __shared__ float Bc[32 * DIM];      // 16 KB
    const int tid = threadIdx.x;
    const int rt = tid >> 4, ct = tid & 15;
    const int e0 = blockIdx.x * TROWS;

    // stage f tile, zero-pad cols [50,52)
    for (int i = tid; i < TROWS * NBP; i += BLK) {
        int row = i / NBP, c = i % NBP;
        int e = e0 + row;
        float v = 0.f;
        if (c < NB && e < N_EDGES_C) v = f_ij[(size_t)e * NB + c];
        fA[row * NBP + c] = v;
    }

    float acc[4][8];
    init_acc_bias(acc, b_f1, ct);
    gemm_tile<NBP, NB>(fA, NBP, W_f1, Bc, acc, rt, ct, tid);

    // ssp -> t1 in LDS
#pragma unroll
    for (int i = 0; i < 4; ++i)
#pragma unroll
        for (int j = 0; j < 8; ++j)
            t1[(rt * 4 + i) * LDA + ct * 8 + j] = ssp_f(acc[i][j]);

    init_acc_bias(acc, b_f2, ct);
    gemm_tile<DIM, DIM>(t1, LDA, W_f2, Bc, acc, rt, ct, tid);

    // epilogue: cutoff, gather h[ind_j], scatter-add agg[ind_i]
#pragma unroll
    for (int i = 0; i < 4; ++i) {
        int e = e0 + rt * 4 + i;
        if (e >= N_EDGES_C) continue;
        float r = r_ij[e];
        float C = (r < 5.0f) ? 0.5f * (cosf(r * PI_OVER_CUT) + 1.0f) : 0.0f;
        int nj = ind_j[e];
        int ni = ind_i[e];
        const float* hp = &h[(size_t)nj * DIM + ct * 8];
        float4 h0 = *(const float4*)hp;
        float4 h1 = *(const float4*)(hp + 4);
        float* ap = &agg[(size_t)ni * DIM + ct * 8];
        atomicAdd(ap + 0, h0.x * acc[i][0] * C);
        atomicAdd(ap + 1, h0.y * acc[i][1] * C);
        atomicAdd(ap + 2, h0.z * acc[i][2] * C);
        atomicAdd(ap + 3, h0.w * acc[i][3] * C);
        atomicAdd(ap + 4, h1.x * acc[i][4] * C);
        atomicAdd(ap + 5, h1.y * acc[i][5] * C);
        atomicAdd(ap + 6, h1.z * acc[i][6] * C);
        atomicAdd(ap + 7, h1.w * acc[i][7] * C);
    }
}

// ---------------- Kernel 3: out = ssp(agg@W_out + b_out) @ W_lin + b_lin ----------------
__global__ __launch_bounds__(BLK) void node_out_kernel(const float* __restrict__ agg,
                                                       const float* __restrict__ W_out,
                                                       const float* __restrict__ b_out,
                                                       const float* __restrict__ W_lin,
                                                       const float* __restrict__ b_lin,
                                                       float* __restrict__ out) {
    __shared__ float At[TROWS * LDA];
    __shared__ float Bc[32 * DIM];
    const int tid = threadIdx.x;
    const int rt = tid >> 4, ct = tid & 15;
    const int n0 = blockIdx.x * TROWS;

    for (int i = tid; i < TROWS * (DIM / 4); i += BLK) {
        int row = i >> 5, c4 = i & 31;
        *(float4*)&At[row * LDA + c4 * 4] = *(const float4*)&agg[(size_t)(n0 + row) * DIM + c4 * 4];
    }

    float acc[4][8];
    init_acc_bias(acc, b_out, ct);
    gemm_tile<DIM, DIM>(At, LDA, W_out, Bc, acc, rt, ct, tid);

    // v = ssp(acc); overwrite At with v
    __syncthreads();  // all reads of At done
#pragma unroll
    for (int i = 0; i < 4; ++i)
#pragma unroll
        for (int j = 0; j < 8; ++j)
            At[(rt * 4 + i) * LDA + ct * 8 + j] = ssp_f(acc[i][j]);

    init_acc_bias(acc, b_lin, ct);
    gemm_tile<DIM, DIM>(At, LDA, W_lin, Bc, acc, rt, ct, tid);

#pragma unroll
    for (int i = 0; i < 4; ++i) {
        float* op = &out[(size_t)(n0 + rt * 4 + i) * DIM + ct * 8];
        *(float4*)op = make_float4(acc[i][0], acc[i][1], acc[i][2], acc[i][3]);
        *(float4*)(op + 4) = make_float4(acc[i][4], acc[i][5], acc[i][6], acc[i][7]);
    }
}

extern "C" void kernel_launch(void* const* d_in, const int* in_sizes, int n_in,
                              void* d_out, int out_size, void* d_ws, size_t ws_size,
                              hipStream_t stream) {
    const float* x      = (const float*)d_in[0];
    const float* r_ij   = (const float*)d_in[1];
    const float* f_ij   = (const float*)d_in[2];
    const int*   ind_i  = (const int*)d_in[3];
    const int*   ind_j  = (const int*)d_in[4];
    const float* W_in2f = (const float*)d_in[5];
    const float* W_f1   = (const float*)d_in[6];
    const float* b_f1   = (const float*)d_in[7];
    const float* W_f2   = (const float*)d_in[8];
    const float* b_f2   = (const float*)d_in[9];
    const float* W_out  = (const float*)d_in[10];
    const float* b_out  = (const float*)d_in[11];
    const float* W_lin  = (const float*)d_in[12];
    const float* b_lin  = (const float*)d_in[13];
    float* out = (float*)d_out;

    float* h   = (float*)d_ws;                          // 40000*128 f32 = 20.48 MB
    float* agg = h + (size_t)N_NODES_C * DIM;           // another 20.48 MB

    hipMemsetAsync(agg, 0, (size_t)N_NODES_C * DIM * sizeof(float), stream);

    node_in2f_kernel<<<N_NODES_C / TROWS, BLK, 0, stream>>>(x, W_in2f, h);
    edge_kernel<<<(N_EDGES_C + TROWS - 1) / TROWS, BLK, 0, stream>>>(
        f_ij, r_ij, ind_i, ind_j, W_f1, b_f1, W_f2, b_f2, h, agg);
    node_out_kernel<<<N_NODES_C / TROWS, BLK, 0, stream>>>(agg, W_out, b_out, W_lin, b_lin, out);
}

// Round 2
// 983.378 us; speedup vs baseline: 2.7988x; 2.7988x over previous
//
#include <hip/hip_runtime.h>

#define N_NODES_C 40000
#define N_EDGES_C 640000
#define DIM 128
#define NB 50
#define NBP 52        // padded basis (multiple of 4)
#define LDA 132       // padded A-tile leading dim
#define BLK 256
#define TROWS 64
#define LOG2_C 0.6931471805599453f
#define PI_OVER_CUT 0.6283185307179586f  // pi/5
#define NSCAN_BLK 157  // ceil(40000/256)

__device__ __forceinline__ float ssp_f(float t) {
    return fmaxf(t, 0.0f) + log1pf(expf(-fabsf(t))) - LOG2_C;
}

// Stage a 32-row chunk of B[K][128] (row-major) into LDS; rows >= Kreal zeroed.
__device__ __forceinline__ void stage_chunk(const float* __restrict__ B, int k0, int rows,
                                            int Kreal, float* __restrict__ Bc, int tid) {
    const int n4 = rows * (DIM / 4);
    const float4* Bg = (const float4*)B + (size_t)k0 * (DIM / 4);
    float4* Bc4 = (float4*)Bc;
    for (int i = tid; i < n4; i += BLK) {
        int row = k0 + (i >> 5);
        float4 v;
        if (row < Kreal) v = Bg[i];
        else v = make_float4(0.f, 0.f, 0.f, 0.f);
        Bc4[i] = v;
    }
}

template <int KPAD, int KREAL>
__device__ __forceinline__ void gemm_tile(const float* __restrict__ A_lds, int lda,
                                          const float* __restrict__ Bglob,
                                          float* __restrict__ Bc,
                                          float acc[4][8], int rt, int ct, int tid) {
    for (int k0 = 0; k0 < KPAD; k0 += 32) {
        const int rows = (KPAD - k0) < 32 ? (KPAD - k0) : 32;
        __syncthreads();
        stage_chunk(Bglob, k0, rows, KREAL, Bc, tid);
        __syncthreads();
        for (int k4 = 0; k4 < rows / 4; ++k4) {
            float4 av[4];
#pragma unroll
            for (int i = 0; i < 4; ++i)
                av[i] = *(const float4*)&A_lds[(rt * 4 + i) * lda + k0 + k4 * 4];
#pragma unroll
            for (int kk = 0; kk < 4; ++kk) {
                const float* bp = &Bc[(k4 * 4 + kk) * DIM + ct * 8];
                float4 b0 = *(const float4*)bp;
                float4 b1 = *(const float4*)(bp + 4);
#pragma unroll
                for (int i = 0; i < 4; ++i) {
                    float a = ((const float*)&av[i])[kk];
                    acc[i][0] += a * b0.x;
                    acc[i][1] += a * b0.y;
                    acc[i][2] += a * b0.z;
                    acc[i][3] += a * b0.w;
                    acc[i][4] += a * b1.x;
                    acc[i][5] += a * b1.y;
                    acc[i][6] += a * b1.z;
                    acc[i][7] += a * b1.w;
                }
            }
        }
    }
}

__device__ __forceinline__ void init_acc_bias(float acc[4][8], const float* __restrict__ b, int ct) {
    float4 bb0 = *(const float4*)&b[ct * 8];
    float4 bb1 = *(const float4*)&b[ct * 8 + 4];
#pragma unroll
    for (int i = 0; i < 4; ++i) {
        acc[i][0] = bb0.x; acc[i][1] = bb0.y; acc[i][2] = bb0.z; acc[i][3] = bb0.w;
        acc[i][4] = bb1.x; acc[i][5] = bb1.y; acc[i][6] = bb1.z; acc[i][7] = bb1.w;
    }
}

// ---------------- Kernel: h = x @ W_in2f ----------------
__global__ __launch_bounds__(BLK) void node_in2f_kernel(const float* __restrict__ x,
                                                        const float* __restrict__ W,
                                                        float* __restrict__ h) {
    __shared__ float At[TROWS * LDA];
    __shared__ float Bc[32 * DIM];
    const int tid = threadIdx.x;
    const int rt = tid >> 4, ct = tid & 15;
    const int n0 = blockIdx.x * TROWS;

    for (int i = tid; i < TROWS * (DIM / 4); i += BLK) {
        int row = i >> 5, c4 = i & 31;
        *(float4*)&At[row * LDA + c4 * 4] = *(const float4*)&x[(size_t)(n0 + row) * DIM + c4 * 4];
    }

    float acc[4][8];
#pragma unroll
    for (int i = 0; i < 4; ++i)
#pragma unroll
        for (int j = 0; j < 8; ++j) acc[i][j] = 0.f;

    gemm_tile<DIM, DIM>(At, LDA, W, Bc, acc, rt, ct, tid);

#pragma unroll
    for (int i = 0; i < 4; ++i) {
        float* hp = &h[(size_t)(n0 + rt * 4 + i) * DIM + ct * 8];
        *(float4*)hp = make_float4(acc[i][0], acc[i][1], acc[i][2], acc[i][3]);
        *(float4*)(hp + 4) = make_float4(acc[i][4], acc[i][5], acc[i][6], acc[i][7]);
    }
}

// ---------------- CSR build ----------------
__global__ __launch_bounds__(BLK) void hist_kernel(const int* __restrict__ ind_i,
                                                   int* __restrict__ cnt) {
    int e = blockIdx.x * BLK + threadIdx.x;
    if (e < N_EDGES_C) atomicAdd(&cnt[ind_i[e]], 1);
}

__global__ __launch_bounds__(BLK) void scan1_kernel(const int* __restrict__ cnt,
                                                    int* __restrict__ excl,
                                                    int* __restrict__ bsum) {
    __shared__ int s[BLK];
    const int tid = threadIdx.x;
    const int idx = blockIdx.x * BLK + tid;
    int v = (idx < N_NODES_C) ? cnt[idx] : 0;
    s[tid] = v;
    __syncthreads();
    for (int off = 1; off < BLK; off <<= 1) {
        int t = (tid >= off) ? s[tid - off] : 0;
        __syncthreads();
        s[tid] += t;
        __syncthreads();
    }
    if (idx < N_NODES_C) excl[idx] = s[tid] - v;
    if (tid == BLK - 1) bsum[blockIdx.x] = s[tid];
}

__global__ __launch_bounds__(BLK) void scan2_kernel(int* __restrict__ bsum) {
    __shared__ int s[BLK];
    const int tid = threadIdx.x;
    int v = (tid < NSCAN_BLK) ? bsum[tid] : 0;
    s[tid] = v;
    __syncthreads();
    for (int off = 1; off < BLK; off <<= 1) {
        int t = (tid >= off) ? s[tid - off] : 0;
        __syncthreads();
        s[tid] += t;
        __syncthreads();
    }
    if (tid < NSCAN_BLK) bsum[tid] = s[tid] - v;  // exclusive
}

__global__ __launch_bounds__(BLK) void scan3_kernel(int* __restrict__ start,
                                                    int* __restrict__ cursor,
                                                    const int* __restrict__ bsum) {
    const int idx = blockIdx.x * BLK + threadIdx.x;
    if (idx < N_NODES_C) {
        int v = start[idx] + bsum[blockIdx.x];
        start[idx] = v;
        cursor[idx] = v;
    }
}

__global__ __launch_bounds__(BLK) void place_kernel(const int* __restrict__ ind_i,
                                                    int* __restrict__ cursor,
                                                    int* __restrict__ eids) {
    int e = blockIdx.x * BLK + threadIdx.x;
    if (e < N_EDGES_C) {
        int slot = atomicAdd(&cursor[ind_i[e]], 1);
        eids[slot] = e;
    }
}

// ---------------- Edge kernel (msg variant, no fp32 atomics) ----------------
__global__ __launch_bounds__(BLK) void edge_kernel_msg(const float* __restrict__ f_ij,
                                                       const float* __restrict__ r_ij,
                                                       const int* __restrict__ ind_j,
                                                       const float* __restrict__ W_f1,
                                                       const float* __restrict__ b_f1,
                                                       const float* __restrict__ W_f2,
                                                       const float* __restrict__ b_f2,
                                                       const float* __restrict__ h,
                                                       float* __restrict__ msg) {
    __shared__ float fA[TROWS * NBP];
    __shared__ float t1[TROWS * LDA];
    __shared__ float Bc[32 * DIM];
    const int tid = threadIdx.x;
    const int rt = tid >> 4, ct = tid & 15;
    const int e0 = blockIdx.x * TROWS;

    for (int i = tid; i < TROWS * NBP; i += BLK) {
        int row = i / NBP, c = i % NBP;
        int e = e0 + row;
        float v = 0.f;
        if (c < NB && e < N_EDGES_C) v = f_ij[(size_t)e * NB + c];
        fA[row * NBP + c] = v;
    }

    float acc[4][8];
    init_acc_bias(acc, b_f1, ct);
    gemm_tile<NBP, NB>(fA, NBP, W_f1, Bc, acc, rt, ct, tid);

#pragma unroll
    for (int i = 0; i < 4; ++i)
#pragma unroll
        for (int j = 0; j < 8; ++j)
            t1[(rt * 4 + i) * LDA + ct * 8 + j] = ssp_f(acc[i][j]);

    init_acc_bias(acc, b_f2, ct);
    gemm_tile<DIM, DIM>(t1, LDA, W_f2, Bc, acc, rt, ct, tid);

#pragma unroll
    for (int i = 0; i < 4; ++i) {
        int e = e0 + rt * 4 + i;
        if (e >= N_EDGES_C) continue;
        float r = r_ij[e];
        float C = (r < 5.0f) ? 0.5f * (cosf(r * PI_OVER_CUT) + 1.0f) : 0.0f;
        int nj = ind_j[e];
        const float* hp = &h[(size_t)nj * DIM + ct * 8];
        float4 h0 = *(const float4*)hp;
        float4 h1 = *(const float4*)(hp + 4);
        float* mp = &msg[(size_t)e * DIM + ct * 8];
        *(float4*)mp = make_float4(h0.x * acc[i][0] * C, h0.y * acc[i][1] * C,
                                   h0.z * acc[i][2] * C, h0.w * acc[i][3] * C);
        *(float4*)(mp + 4) = make_float4(h1.x * acc[i][4] * C, h1.y * acc[i][5] * C,
                                         h1.z * acc[i][6] * C, h1.w * acc[i][7] * C);
    }
}

// ---------------- Gather: agg[n] = sum over CSR edges of msg ----------------
__global__ __launch_bounds__(BLK) void gather_kernel(const float* __restrict__ msg,
                                                     const int* __restrict__ eids,
                                                     const int* __restrict__ start,
                                                     const int* __restrict__ cnt,
                                                     float* __restrict__ agg) {
    const int wave = threadIdx.x >> 6;
    const int lane = threadIdx.x & 63;
    const int node = blockIdx.x * 4 + wave;
    if (node >= N_NODES_C) return;
    const int s = start[node];
    const int d = cnt[node];
    float ax = 0.f, ay = 0.f;
    int k = 0;
    for (; k + 1 < d; k += 2) {
        int ea = eids[s + k], eb = eids[s + k + 1];
        float2 va = *(const float2*)&msg[(size_t)ea * DIM + lane * 2];
        float2 vb = *(const float2*)&msg[(size_t)eb * DIM + lane * 2];
        ax += va.x + vb.x;
        ay += va.y + vb.y;
    }
    if (k < d) {
        int ea = eids[s + k];
        float2 va = *(const float2*)&msg[(size_t)ea * DIM + lane * 2];
        ax += va.x;
        ay += va.y;
    }
    *(float2*)&agg[(size_t)node * DIM + lane * 2] = make_float2(ax, ay);
}

// ---------------- Edge kernel (atomic fallback) ----------------
__global__ __launch_bounds__(BLK) void edge_kernel_atomic(const float* __restrict__ f_ij,
                                                          const float* __restrict__ r_ij,
                                                          const int* __restrict__ ind_i,
                                                          const int* __restrict__ ind_j,
                                                          const float* __restrict__ W_f1,
                                                          const float* __restrict__ b_f1,
                                                          const float* __restrict__ W_f2,
                                                          const float* __restrict__ b_f2,
                                                          const float* __restrict__ h,
                                                          float* __restrict__ agg) {
    __shared__ float fA[TROWS * NBP];
    __shared__ float t1[TROWS * LDA];
    __shared__ float Bc[32 * DIM];
    const int tid = threadIdx.x;
    const int rt = tid >> 4, ct = tid & 15;
    const int e0 = blockIdx.x * TROWS;

    for (int i = tid; i < TROWS * NBP; i += BLK) {
        int row = i / NBP, c = i % NBP;
        int e = e0 + row;
        float v = 0.f;
        if (c < NB && e < N_EDGES_C) v = f_ij[(size_t)e * NB + c];
        fA[row * NBP + c] = v;
    }

    float acc[4][8];
    init_acc_bias(acc, b_f1, ct);
    gemm_tile<NBP, NB>(fA, NBP, W_f1, Bc, acc, rt, ct, tid);

#pragma unroll
    for (int i = 0; i < 4; ++i)
#pragma unroll
        for (int j = 0; j < 8; ++j)
            t1[(rt * 4 + i) * LDA + ct * 8 + j] = ssp_f(acc[i][j]);

    init_acc_bias(acc, b_f2, ct);
    gemm_tile<DIM, DIM>(t1, LDA, W_f2, Bc, acc, rt, ct, tid);

#pragma unroll
    for (int i = 0; i < 4; ++i) {
        int e = e0 + rt * 4 + i;
        if (e >= N_EDGES_C) continue;
        float r = r_ij[e];
        float C = (r < 5.0f) ? 0.5f * (cosf(r * PI_OVER_CUT) + 1.0f) : 0.0f;
        int nj = ind_j[e];
        int ni = ind_i[e];
        const float* hp = &h[(size_t)nj * DIM + ct * 8];
        float4 h0 = *(const float4*)hp;
        float4 h1 = *(const float4*)(hp + 4);
        float* ap = &agg[(size_t)ni * DIM + ct * 8];
        atomicAdd(ap + 0, h0.x * acc[i][0] * C);
        atomicAdd(ap + 1, h0.y * acc[i][1] * C);
        atomicAdd(ap + 2, h0.z * acc[i][2] * C);
        atomicAdd(ap + 3, h0.w * acc[i][3] * C);
        atomicAdd(ap + 4, h1.x * acc[i][4] * C);
        atomicAdd(ap + 5, h1.y * acc[i][5] * C);
        atomicAdd(ap + 6, h1.z * acc[i][6] * C);
        atomicAdd(ap + 7, h1.w * acc[i][7] * C);
    }
}

// ---------------- Output: out = ssp(agg@W_out + b_out) @ W_lin + b_lin ----------------
__global__ __launch_bounds__(BLK) void node_out_kernel(const float* __restrict__ agg,
                                                       const float* __restrict__ W_out,
                                                       const float* __restrict__ b_out,
                                                       const float* __restrict__ W_lin,
                                                       const float* __restrict__ b_lin,
                                                       float* __restrict__ out) {
    __shared__ float At[TROWS * LDA];
    __shared__ float Bc[32 * DIM];
    const int tid = threadIdx.x;
    const int rt = tid >> 4, ct = tid & 15;
    const int n0 = blockIdx.x * TROWS;

    for (int i = tid; i < TROWS * (DIM / 4); i += BLK) {
        int row = i >> 5, c4 = i & 31;
        *(float4*)&At[row * LDA + c4 * 4] = *(const float4*)&agg[(size_t)(n0 + row) * DIM + c4 * 4];
    }

    float acc[4][8];
    init_acc_bias(acc, b_out, ct);
    gemm_tile<DIM, DIM>(At, LDA, W_out, Bc, acc, rt, ct, tid);

    __syncthreads();
#pragma unroll
    for (int i = 0; i < 4; ++i)
#pragma unroll
        for (int j = 0; j < 8; ++j)
            At[(rt * 4 + i) * LDA + ct * 8 + j] = ssp_f(acc[i][j]);

    init_acc_bias(acc, b_lin, ct);
    gemm_tile<DIM, DIM>(At, LDA, W_lin, Bc, acc, rt, ct, tid);

#pragma unroll
    for (int i = 0; i < 4; ++i) {
        float* op = &out[(size_t)(n0 + rt * 4 + i) * DIM + ct * 8];
        *(float4*)op = make_float4(acc[i][0], acc[i][1], acc[i][2], acc[i][3]);
        *(float4*)(op + 4) = make_float4(acc[i][4], acc[i][5], acc[i][6], acc[i][7]);
    }
}

extern "C" void kernel_launch(void* const* d_in, const int* in_sizes, int n_in,
                              void* d_out, int out_size, void* d_ws, size_t ws_size,
                              hipStream_t stream) {
    const float* x      = (const float*)d_in[0];
    const float* r_ij   = (const float*)d_in[1];
    const float* f_ij   = (const float*)d_in[2];
    const int*   ind_i  = (const int*)d_in[3];
    const int*   ind_j  = (const int*)d_in[4];
    const float* W_in2f = (const float*)d_in[5];
    const float* W_f1   = (const float*)d_in[6];
    const float* b_f1   = (const float*)d_in[7];
    const float* W_f2   = (const float*)d_in[8];
    const float* b_f2   = (const float*)d_in[9];
    const float* W_out  = (const float*)d_in[10];
    const float* b_out  = (const float*)d_in[11];
    const float* W_lin  = (const float*)d_in[12];
    const float* b_lin  = (const float*)d_in[13];
    float* out = (float*)d_out;

    char* ws = (char*)d_ws;
    size_t off = 0;
    auto alloc = [&](size_t bytes) {
        char* p = ws + off;
        off = (off + bytes + 511) & ~(size_t)511;
        return p;
    };
    float* h      = (float*)alloc((size_t)N_NODES_C * DIM * sizeof(float));
    float* agg    = (float*)alloc((size_t)N_NODES_C * DIM * sizeof(float));
    float* msg    = (float*)alloc((size_t)N_EDGES_C * DIM * sizeof(float));
    int*   eids   = (int*)alloc((size_t)N_EDGES_C * sizeof(int));
    int*   cnt    = (int*)alloc((size_t)N_NODES_C * sizeof(int));
    int*   startA = (int*)alloc((size_t)N_NODES_C * sizeof(int));
    int*   cursor = (int*)alloc((size_t)N_NODES_C * sizeof(int));
    int*   bsum   = (int*)alloc((size_t)NSCAN_BLK * sizeof(int));
    const bool have_ws = (off <= ws_size);

    node_in2f_kernel<<<N_NODES_C / TROWS, BLK, 0, stream>>>(x, W_in2f, h);

    if (have_ws) {
        // CSR build
        hipMemsetAsync(cnt, 0, (size_t)N_NODES_C * sizeof(int), stream);
        hist_kernel<<<(N_EDGES_C + BLK - 1) / BLK, BLK, 0, stream>>>(ind_i, cnt);
        scan1_kernel<<<NSCAN_BLK, BLK, 0, stream>>>(cnt, startA, bsum);
        scan2_kernel<<<1, BLK, 0, stream>>>(bsum);
        scan3_kernel<<<NSCAN_BLK, BLK, 0, stream>>>(startA, cursor, bsum);
        place_kernel<<<(N_EDGES_C + BLK - 1) / BLK, BLK, 0, stream>>>(ind_i, cursor, eids);

        edge_kernel_msg<<<(N_EDGES_C + TROWS - 1) / TROWS, BLK, 0, stream>>>(
            f_ij, r_ij, ind_j, W_f1, b_f1, W_f2, b_f2, h, msg);
        gather_kernel<<<(N_NODES_C + 3) / 4, BLK, 0, stream>>>(msg, eids, startA, cnt, agg);
    } else {
        hipMemsetAsync(agg, 0, (size_t)N_NODES_C * DIM * sizeof(float), stream);
        edge_kernel_atomic<<<(N_EDGES_C + TROWS - 1) / TROWS, BLK, 0, stream>>>(
            f_ij, r_ij, ind_i, ind_j, W_f1, b_f1, W_f2, b_f2, h, agg);
    }

    node_out_kernel<<<N_NODES_C / TROWS, BLK, 0, stream>>>(agg, W_out, b_out, W_lin, b_lin, out);
}